// Round 9
// baseline (208.713 us; speedup 1.0000x reference)
//
#include <hip/hip_runtime.h>

#define B_DIM 32
#define C_DIM 64
#define F_DIM 16384
#define O_DIM 128
#define NBLK ((F_DIM / 64) * B_DIM)   // 8192 compute blocks (1 tile of 64 points each)

typedef __attribute__((ext_vector_type(8))) short short8;
typedef __attribute__((ext_vector_type(4))) float f32x4;

__device__ __forceinline__ ushort f2bf(float f) {
    union { float f; uint u; } v; v.f = f;
    return (ushort)((v.u + 0x7FFFu + ((v.u >> 16) & 1u)) >> 16);
}
__device__ __forceinline__ float bflo(uint u) {
    union { uint u; float f; } v; v.u = u << 16; return v.f;
}
__device__ __forceinline__ float bfhi(uint u) {
    union { uint u; float f; } v; v.u = u & 0xFFFF0000u; return v.f;
}
// beta for a packed pair of bf16: |t-n1|+|t-n2|+|t-n3| (lo,hi lanes)
__device__ __forceinline__ uint beta_pair(uint tu, uint au, uint bu, uint cu) {
    const float tl = bflo(tu), th = bfhi(tu);
    const float lo = fabsf(tl - bflo(au)) + fabsf(tl - bflo(bu)) + fabsf(tl - bflo(cu));
    const float hi = fabsf(th - bfhi(au)) + fabsf(th - bfhi(bu)) + fabsf(th - bfhi(cu));
    return (uint)f2bf(lo) | ((uint)f2bf(hi) << 16);
}
__device__ __forceinline__ short8 as_s8(uint4 u) {
    union { uint4 u; short8 s; } cv; cv.u = u; return cv.s;
}

// ------- Pass 1: transpose x (B,C,F) fp32 -> xt (B,F,C) bf16  (+W prep) -----
__global__ __launch_bounds__(256) void k_transpose(const float* __restrict__ x,
                                                   ushort* __restrict__ xt,
                                                   const float* __restrict__ W,
                                                   ushort* __restrict__ Wtg) {
    __shared__ float tile[64][65];
    const int b  = blockIdx.y;
    const int f0 = blockIdx.x * 64;
    const int t  = threadIdx.x;
    const int fl = t & 63;
    const int q  = t >> 6;

    const float* xb = x + (size_t)b * C_DIM * F_DIM;
    #pragma unroll
    for (int i = 0; i < 16; ++i) {
        const int c = q + i * 4;
        tile[c][fl] = __builtin_nontemporal_load(&xb[(size_t)c * F_DIM + f0 + fl]);
    }

    if (blockIdx.x == 0 && blockIdx.y == 0 && t < 128) {
        const int o = t;
        #pragma unroll 8
        for (int c = 0; c < C_DIM; ++c) {
            Wtg[o * 128 + c]      = f2bf(W[o * 128 + c * 2]);
            Wtg[o * 128 + 64 + c] = f2bf(W[o * 128 + c * 2 + 1]);
        }
    }

    __syncthreads();

    const int f  = t >> 2;
    const int ch = t & 3;
    union { ushort s[16]; uint4 v[2]; } u;
    #pragma unroll
    for (int j = 0; j < 16; ++j)
        u.s[j] = f2bf(tile[ch * 16 + j][f]);
    ushort* dst = xt + ((size_t)b * F_DIM + f0 + f) * C_DIM + ch * 16;
    *(uint4*)(dst)     = u.v[0];
    *(uint4*)(dst + 8) = u.v[1];
}

// ------------- Pass 2/4: gather + beta + MFMA, A fully in registers ---------
// Each lane gathers exactly its own MFMA A-fragment chunks (static indexing,
// single tile per block, no double-buffer -- the round-5 spill trap avoided).
// MODE 0: accumulate per-block (sum,sumsq) per o -> part, no y store.
// MODE 1: apply scale/shift (ss) + ReLU, store final y (nontemporal).
template <int MODE>
__global__ __launch_bounds__(256, 4) void k_compute_t(const ushort* __restrict__ xt,
                                                      const int*    __restrict__ adj,
                                                      const ushort* __restrict__ Wtg,
                                                      const float*  __restrict__ bias,
                                                      const float*  __restrict__ ss,
                                                      float*        __restrict__ y,
                                                      float*        __restrict__ part) {
    __shared__ __align__(16) char Wsm[128 * 256];   // Wt: 128 rows x 128 bf16, swizzled

    const int bid = blockIdx.x;
    const int tg  = (bid & 7) * (NBLK / 8) + (bid >> 3);   // XCD-aware, bijective
    const int b   = tg >> 8;                                // 256 tiles per batch
    const int f0  = (tg & 255) * 64;
    const int t   = threadIdx.x;

    const int w     = t >> 6;        // wave 0..3
    const int l     = t & 63;
    const int col16 = l & 15;
    const int g     = l >> 4;        // k-group 0..3
    const int co    = g * 16;        // this lane's byte chunk within a 128B row
    const int p     = w * 16 + col16;   // the A m-row (f-point) this lane owns

    // --- issue this lane's 8 gather loads FIRST (latency overlap) ---
    const int4 a4 = ((const int4*)adj)[(size_t)b * F_DIM + f0 + p];
    const char* xb = (const char*)(xt + (size_t)b * F_DIM * C_DIM);
    const char* r0 = xb + (size_t)a4.x * 128 + co;
    const char* r1 = xb + (size_t)a4.y * 128 + co;
    const char* r2 = xb + (size_t)a4.z * 128 + co;
    const char* r3 = xb + (size_t)a4.w * 128 + co;
    uint4 g0 = *(const uint4*)(r0);
    uint4 g1 = *(const uint4*)(r0 + 64);
    uint4 g2 = *(const uint4*)(r1);
    uint4 g3 = *(const uint4*)(r1 + 64);
    uint4 g4 = *(const uint4*)(r2);
    uint4 g5 = *(const uint4*)(r2 + 64);
    uint4 g6 = *(const uint4*)(r3);
    uint4 g7 = *(const uint4*)(r3 + 64);

    // --- stage Wt into swizzled LDS (independent work under gather latency) ---
    {
        const uint4* src = (const uint4*)Wtg;
        #pragma unroll
        for (int jj = 0; jj < 8; ++jj) {
            const int fb    = t * 128 + jj * 16;
            const int o     = fb >> 8;
            const int inner = fb & 255;
            *(uint4*)(Wsm + (o << 8) + (inner ^ ((o & 7) << 4))) = src[fb >> 4];
        }
    }
    __syncthreads();   // single barrier; Wsm read-only hereafter

    // --- A fragments in registers ---
    // af[0]: target k=g*8..+8 ; af[1]: target k=32+g*8 ; af[2],af[3]: beta
    short8 af0 = as_s8(g0);
    short8 af1 = as_s8(g1);
    short8 af2 = as_s8(make_uint4(beta_pair(g0.x, g2.x, g4.x, g6.x),
                                  beta_pair(g0.y, g2.y, g4.y, g6.y),
                                  beta_pair(g0.z, g2.z, g4.z, g6.z),
                                  beta_pair(g0.w, g2.w, g4.w, g6.w)));
    short8 af3 = as_s8(make_uint4(beta_pair(g1.x, g3.x, g5.x, g7.x),
                                  beta_pair(g1.y, g3.y, g5.y, g7.y),
                                  beta_pair(g1.z, g3.z, g5.z, g7.z),
                                  beta_pair(g1.w, g3.w, g5.w, g7.w)));

    f32x4 acc[8];
    #pragma unroll
    for (int s = 0; s < 8; ++s) {
        const float bv = bias[s * 16 + col16];
        acc[s] = (f32x4){ bv, bv, bv, bv };
    }

    const int swl = (col16 & 7) << 4;
    #pragma unroll
    for (int s = 0; s < 8; ++s) {
        const char* Wrow = Wsm + (s * 16 + col16) * 256;
        acc[s] = __builtin_amdgcn_mfma_f32_16x16x32_bf16(
                     af0, *(const short8*)(Wrow + ((0 * 64 + g * 16) ^ swl)), acc[s], 0, 0, 0);
        acc[s] = __builtin_amdgcn_mfma_f32_16x16x32_bf16(
                     af1, *(const short8*)(Wrow + ((1 * 64 + g * 16) ^ swl)), acc[s], 0, 0, 0);
        acc[s] = __builtin_amdgcn_mfma_f32_16x16x32_bf16(
                     af2, *(const short8*)(Wrow + ((2 * 64 + g * 16) ^ swl)), acc[s], 0, 0, 0);
        acc[s] = __builtin_amdgcn_mfma_f32_16x16x32_bf16(
                     af3, *(const short8*)(Wrow + ((3 * 64 + g * 16) ^ swl)), acc[s], 0, 0, 0);
    }

    if (MODE == 0) {
        // --- reduce acc -> per-block (sum,sumsq) per o, write partials ---
        __shared__ float sm_s[4][128];
        __shared__ float sm_q[4][128];
        #pragma unroll
        for (int s = 0; s < 8; ++s) {
            float ps = acc[s].x + acc[s].y + acc[s].z + acc[s].w;
            float pq = acc[s].x * acc[s].x + acc[s].y * acc[s].y
                     + acc[s].z * acc[s].z + acc[s].w * acc[s].w;
            ps += __shfl_xor(ps, 16, 64);  pq += __shfl_xor(pq, 16, 64);
            ps += __shfl_xor(ps, 32, 64);  pq += __shfl_xor(pq, 32, 64);
            if (g == 0) {
                sm_s[w][s * 16 + col16] = ps;
                sm_q[w][s * 16 + col16] = pq;
            }
        }
        __syncthreads();
        if (t < 128) {
            const float a = sm_s[0][t] + sm_s[1][t] + sm_s[2][t] + sm_s[3][t];
            const float c = sm_q[0][t] + sm_q[1][t] + sm_q[2][t] + sm_q[3][t];
            part[(size_t)t * NBLK + bid]         = a;
            part[(size_t)(128 + t) * NBLK + bid] = c;
        }
    } else {
        // MODE 1: normalize + ReLU + coalesced nontemporal float4 stores
        const int fbase = f0 + w * 16 + g * 4;
        #pragma unroll
        for (int s = 0; s < 8; ++s) {
            const int o = s * 16 + col16;
            const float sc = ss[o];
            const float sh = ss[O_DIM + o];
            f32x4 v = acc[s];
            v.x = fmaxf(fmaf(v.x, sc, sh), 0.f);
            v.y = fmaxf(fmaf(v.y, sc, sh), 0.f);
            v.z = fmaxf(fmaf(v.z, sc, sh), 0.f);
            v.w = fmaxf(fmaf(v.w, sc, sh), 0.f);
            __builtin_nontemporal_store(v, (f32x4*)(y + ((size_t)b * O_DIM + o) * F_DIM + fbase));
        }
    }
}

// ------------- Pass 3: reduce partials + finalize scale/shift ---------------
__global__ __launch_bounds__(256) void k_reduce_finalize(const float* __restrict__ part,
                                                         const float* __restrict__ gamma,
                                                         const float* __restrict__ beta_bn,
                                                         float* __restrict__ ss) {
    const int o = blockIdx.x;
    const int t = threadIdx.x;
    const float4* p1 = (const float4*)(part + (size_t)o * NBLK);
    const float4* p2 = (const float4*)(part + (size_t)(128 + o) * NBLK);
    float s = 0.f, q = 0.f;
    for (int i = t; i < NBLK / 4; i += 256) {
        const float4 v = p1[i];
        s += v.x + v.y + v.z + v.w;
        const float4 u = p2[i];
        q += u.x + u.y + u.z + u.w;
    }
    #pragma unroll
    for (int off = 32; off > 0; off >>= 1) {
        s += __shfl_down(s, off, 64);
        q += __shfl_down(q, off, 64);
    }
    __shared__ float ls[8];
    const int wid = t >> 6, lane = t & 63;
    if (lane == 0) { ls[wid] = s; ls[4 + wid] = q; }
    __syncthreads();
    if (t == 0) {
        const float ts = ls[0] + ls[1] + ls[2] + ls[3];
        const float tq = ls[4] + ls[5] + ls[6] + ls[7];
        const float n    = (float)B_DIM * (float)F_DIM;
        const float mean = ts / n;
        const float var  = tq / n - mean * mean;
        const float sc   = gamma[o] * rsqrtf(var + 1e-5f);
        ss[o]         = sc;
        ss[O_DIM + o] = beta_bn[o] - mean * sc;
    }
}

// ================== fallback path (small ws) — round-1 known-correct ========
__global__ __launch_bounds__(256) void k_compute_slow(const float* __restrict__ xsrc,
                                                      const int*   __restrict__ adj,
                                                      const float* __restrict__ W,
                                                      const float* __restrict__ bias,
                                                      float*       __restrict__ y) {
    const int b = blockIdx.y;
    const int f = blockIdx.x * 256 + threadIdx.x;
    const int4 a = ((const int4*)adj)[(size_t)b * F_DIM + f];
    float tg[64], bt[64];
    const float* base = xsrc + (size_t)b * C_DIM * F_DIM;
    #pragma unroll
    for (int c = 0; c < 64; ++c) {
        const float tv = base[(size_t)c * F_DIM + a.x];
        const float n1 = base[(size_t)c * F_DIM + a.y];
        const float n2 = base[(size_t)c * F_DIM + a.z];
        const float n3 = base[(size_t)c * F_DIM + a.w];
        tg[c] = tv;
        bt[c] = fabsf(tv - n1) + fabsf(tv - n2) + fabsf(tv - n3);
    }
    float* yb = y + (size_t)b * O_DIM * F_DIM + f;
    const float2* W2 = (const float2*)W;
    #pragma unroll 4
    for (int o = 0; o < O_DIM; ++o) {
        float acc = bias[o];
        #pragma unroll
        for (int c = 0; c < 64; ++c) {
            const float2 wv = W2[o * 64 + c];
            acc = fmaf(tg[c], wv.x, fmaf(bt[c], wv.y, acc));
        }
        yb[(size_t)o * F_DIM] = acc;
    }
}

__global__ __launch_bounds__(256) void k_stats(const float* __restrict__ y,
                                               float* __restrict__ stats) {
    const int o = blockIdx.x;
    const int b = blockIdx.y;
    const float4* row = (const float4*)(y + ((size_t)b * O_DIM + o) * F_DIM);
    float s = 0.f, s2 = 0.f;
    for (int i = threadIdx.x; i < F_DIM / 4; i += 256) {
        const float4 v = row[i];
        s  += v.x + v.y + v.z + v.w;
        s2 += v.x * v.x + v.y * v.y + v.z * v.z + v.w * v.w;
    }
    #pragma unroll
    for (int off = 32; off > 0; off >>= 1) {
        s  += __shfl_down(s,  off, 64);
        s2 += __shfl_down(s2, off, 64);
    }
    __shared__ float ls[4], ls2[4];
    const int wid = threadIdx.x >> 6, lane = threadIdx.x & 63;
    if (lane == 0) { ls[wid] = s; ls2[wid] = s2; }
    __syncthreads();
    if (threadIdx.x == 0) {
        atomicAdd(&stats[o],         ls[0] + ls[1] + ls[2] + ls[3]);
        atomicAdd(&stats[O_DIM + o], ls2[0] + ls2[1] + ls2[2] + ls2[3]);
    }
}

__global__ void k_finalize(const float* __restrict__ stats,
                           const float* __restrict__ gamma,
                           const float* __restrict__ beta_bn,
                           float* __restrict__ ss) {
    const int o = threadIdx.x;
    if (o < O_DIM) {
        const float n    = (float)B_DIM * (float)F_DIM;
        const float mean = stats[o] / n;
        const float var  = stats[O_DIM + o] / n - mean * mean;
        const float sc   = gamma[o] * rsqrtf(var + 1e-5f);
        ss[o]         = sc;
        ss[O_DIM + o] = beta_bn[o] - mean * sc;
    }
}

__global__ __launch_bounds__(256) void k_norm(float* __restrict__ y,
                                              const float* __restrict__ ss) {
    const size_t n4 = (size_t)B_DIM * O_DIM * F_DIM / 4;
    const size_t stride = (size_t)gridDim.x * blockDim.x;
    float4* y4 = (float4*)y;
    for (size_t i = (size_t)blockIdx.x * blockDim.x + threadIdx.x; i < n4; i += stride) {
        const int o = (int)((i >> 12) & (O_DIM - 1));
        const float sc = ss[o];
        const float sh = ss[O_DIM + o];
        float4 v = y4[i];
        v.x = fmaxf(fmaf(v.x, sc, sh), 0.f);
        v.y = fmaxf(fmaf(v.y, sc, sh), 0.f);
        v.z = fmaxf(fmaf(v.z, sc, sh), 0.f);
        v.w = fmaxf(fmaf(v.w, sc, sh), 0.f);
        y4[i] = v;
    }
}

extern "C" void kernel_launch(void* const* d_in, const int* in_sizes, int n_in,
                              void* d_out, int out_size, void* d_ws, size_t ws_size,
                              hipStream_t stream) {
    const float* x       = (const float*)d_in[0];
    const int*   adj     = (const int*)  d_in[1];
    const float* W       = (const float*)d_in[2];
    const float* bias    = (const float*)d_in[3];
    const float* gamma   = (const float*)d_in[4];
    const float* beta_bn = (const float*)d_in[5];
    float* out = (float*)d_out;

    const size_t XT_B   = (size_t)B_DIM * F_DIM * C_DIM * 2;          // 64 MB
    const size_t PART_B = (size_t)2 * O_DIM * NBLK * sizeof(float);   // 8 MB

    float*  stats = (float*)d_ws;
    float*  ss    = (float*)((char*)d_ws + 1024);
    ushort* Wtg   = (ushort*)((char*)d_ws + 4096);
    ushort* xt    = (ushort*)((char*)d_ws + 65536);
    float*  part  = (float*)((char*)d_ws + 65536 + XT_B);

    const size_t need = 65536 + XT_B + PART_B;

    if (ws_size >= need) {
        k_transpose<<<dim3(F_DIM / 64, B_DIM), 256, 0, stream>>>(x, xt, W, Wtg);
        k_compute_t<0><<<dim3(NBLK), 256, 0, stream>>>(xt, adj, Wtg, bias, nullptr, nullptr, part);
        k_reduce_finalize<<<O_DIM, 256, 0, stream>>>(part, gamma, beta_bn, ss);
        k_compute_t<1><<<dim3(NBLK), 256, 0, stream>>>(xt, adj, Wtg, bias, ss, out, nullptr);
    } else {
        hipMemsetAsync(stats, 0, 2 * O_DIM * sizeof(float), stream);
        k_compute_slow<<<dim3(F_DIM / 256, B_DIM), 256, 0, stream>>>(x, adj, W, bias, out);
        k_stats<<<dim3(O_DIM, B_DIM), 256, 0, stream>>>(out, stats);
        k_finalize<<<1, 128, 0, stream>>>(stats, gamma, beta_bn, ss);
        k_norm<<<2048, 256, 0, stream>>>(out, ss);
    }
}

// Round 10
// 208.631 us; speedup vs baseline: 1.0004x; 1.0004x over previous
//
#include <hip/hip_runtime.h>

#define B_DIM 32
#define C_DIM 64
#define F_DIM 16384
#define O_DIM 128
#define NBLK  ((F_DIM / 64) * B_DIM)   // 8192 tiles of 64 points
#define TPB   8                         // tiles per block (pipelined)
#define NBLK3 (NBLK / TPB)              // 1024 compute blocks

typedef __attribute__((ext_vector_type(8))) short short8;
typedef __attribute__((ext_vector_type(4))) float f32x4;

__device__ __forceinline__ ushort f2bf(float f) {
    union { float f; uint u; } v; v.f = f;
    return (ushort)((v.u + 0x7FFFu + ((v.u >> 16) & 1u)) >> 16);
}
__device__ __forceinline__ float bflo(uint u) {
    union { uint u; float f; } v; v.u = u << 16; return v.f;
}
__device__ __forceinline__ float bfhi(uint u) {
    union { uint u; float f; } v; v.u = u & 0xFFFF0000u; return v.f;
}
__device__ __forceinline__ uint beta_pair(uint tu, uint au, uint bu, uint cu) {
    const float tl = bflo(tu), th = bfhi(tu);
    const float lo = fabsf(tl - bflo(au)) + fabsf(tl - bflo(bu)) + fabsf(tl - bflo(cu));
    const float hi = fabsf(th - bfhi(au)) + fabsf(th - bfhi(bu)) + fabsf(th - bfhi(cu));
    return (uint)f2bf(lo) | ((uint)f2bf(hi) << 16);
}

// ------- Pass 1: transpose x (B,C,F) fp32 -> xt (B,F,C) bf16  (+W prep) -----
__global__ __launch_bounds__(256) void k_transpose(const float* __restrict__ x,
                                                   ushort* __restrict__ xt,
                                                   const float* __restrict__ W,
                                                   ushort* __restrict__ Wtg) {
    __shared__ float tile[64][65];
    const int b  = blockIdx.y;
    const int f0 = blockIdx.x * 64;
    const int t  = threadIdx.x;
    const int fl = t & 63;
    const int q  = t >> 6;

    const float* xb = x + (size_t)b * C_DIM * F_DIM;
    #pragma unroll
    for (int i = 0; i < 16; ++i) {
        const int c = q + i * 4;
        tile[c][fl] = __builtin_nontemporal_load(&xb[(size_t)c * F_DIM + f0 + fl]);
    }

    if (blockIdx.x == 0 && blockIdx.y == 0 && t < 128) {
        const int o = t;
        #pragma unroll 8
        for (int c = 0; c < C_DIM; ++c) {
            Wtg[o * 128 + c]      = f2bf(W[o * 128 + c * 2]);
            Wtg[o * 128 + 64 + c] = f2bf(W[o * 128 + c * 2 + 1]);
        }
    }

    __syncthreads();

    const int f  = t >> 2;
    const int ch = t & 3;
    union { ushort s[16]; uint4 v[2]; } u;
    #pragma unroll
    for (int j = 0; j < 16; ++j)
        u.s[j] = f2bf(tile[ch * 16 + j][f]);
    ushort* dst = xt + ((size_t)b * F_DIM + f0 + f) * C_DIM + ch * 16;
    *(uint4*)(dst)     = u.v[0];
    *(uint4*)(dst + 8) = u.v[1];
}

// ------------- Pass 2/4: pipelined gather + beta + MFMA (8 tiles/block) -----
// Round-8 staging/MFMA code, pipelined: while MFMAs consume tile i from LDS,
// tile i+1's gathers are in flight into named registers (all static indexing).
// MODE 0: accumulate (sum,sumsq) per o across tiles -> part (1 write/block).
// MODE 1: apply scale/shift + ReLU, store final y (nontemporal).
template <int MODE>
__global__ __launch_bounds__(256, 3) void k_compute_t(const ushort* __restrict__ xt,
                                                      const int*    __restrict__ adj,
                                                      const ushort* __restrict__ Wtg,
                                                      const float*  __restrict__ bias,
                                                      const float*  __restrict__ ss,
                                                      float*        __restrict__ y,
                                                      float*        __restrict__ part) {
    __shared__ __align__(16) char Asm[64 * 256];    // A tile (swizzled)
    __shared__ __align__(16) char Wsm[128 * 256];   // Wt (swizzled)

    const int bid  = blockIdx.x;
    const int tg0  = ((bid & 7) * (NBLK3 / 8) + (bid >> 3)) * TPB; // XCD-aware, bijective
    const int b    = tg0 >> 8;            // TPB divides 256 -> same batch for all 8
    const int tloc = tg0 & 255;           // tile index within batch (aligned to 8)
    const int t    = threadIdx.x;

    const int p  = t >> 2;                // point 0..63
    const int ch = t & 3;                 // 32B c-chunk
    const int4* adjp = (const int4*)adj + (size_t)b * F_DIM;
    const char* xb   = (const char*)(xt + (size_t)b * F_DIM * C_DIM);

    // preload all TPB adj entries (named, static)
    const int4 a0 = adjp[(tloc + 0) * 64 + p];
    const int4 a1 = adjp[(tloc + 1) * 64 + p];
    const int4 a2 = adjp[(tloc + 2) * 64 + p];
    const int4 a3 = adjp[(tloc + 3) * 64 + p];
    const int4 a4_ = adjp[(tloc + 4) * 64 + p];
    const int4 a5 = adjp[(tloc + 5) * 64 + p];
    const int4 a6 = adjp[(tloc + 6) * 64 + p];
    const int4 a7 = adjp[(tloc + 7) * 64 + p];

    uint4 g0, g1, g2, g3, g4, g5, g6, g7;
    #define ISSUE(a)                                                          \
        do {                                                                  \
            g0 = *(const uint4*)(xb + (size_t)(a).x * 128 + ch * 32);         \
            g1 = *(const uint4*)(xb + (size_t)(a).x * 128 + ch * 32 + 16);    \
            g2 = *(const uint4*)(xb + (size_t)(a).y * 128 + ch * 32);         \
            g3 = *(const uint4*)(xb + (size_t)(a).y * 128 + ch * 32 + 16);    \
            g4 = *(const uint4*)(xb + (size_t)(a).z * 128 + ch * 32);         \
            g5 = *(const uint4*)(xb + (size_t)(a).z * 128 + ch * 32 + 16);    \
            g6 = *(const uint4*)(xb + (size_t)(a).w * 128 + ch * 32);         \
            g7 = *(const uint4*)(xb + (size_t)(a).w * 128 + ch * 32 + 16);    \
        } while (0)

    ISSUE(a0);

    // stage Wt into swizzled LDS (under gather latency; once per block)
    {
        const uint4* src = (const uint4*)Wtg;
        #pragma unroll
        for (int jj = 0; jj < 8; ++jj) {
            const int fb    = t * 128 + jj * 16;
            const int o     = fb >> 8;
            const int inner = fb & 255;
            *(uint4*)(Wsm + (o << 8) + (inner ^ ((o & 7) << 4))) = src[fb >> 4];
        }
    }

    const int w     = t >> 6;
    const int l     = t & 63;
    const int col16 = l & 15;
    const int kg    = l >> 4;
    const int swl   = (l & 7) << 4;
    const int swp   = (p & 7) << 4;
    char* Arow = Asm + p * 256;
    const char* ArowR = Asm + (w * 16 + col16) * 256;

    // hoisted per-lane constants
    float bv[8];
    #pragma unroll
    for (int s = 0; s < 8; ++s) bv[s] = bias[s * 16 + col16];
    float scv[8], shv[8];
    if (MODE == 1) {
        #pragma unroll
        for (int s = 0; s < 8; ++s) {
            scv[s] = ss[s * 16 + col16];
            shv[s] = ss[O_DIM + s * 16 + col16];
        }
    }
    float ps[8], pq[8];
    if (MODE == 0) {
        #pragma unroll
        for (int s = 0; s < 8; ++s) { ps[s] = 0.f; pq[s] = 0.f; }
    }

    // write A tile (target + beta) from g0..g7 into swizzled Asm
    #define WRITE_A()                                                              \
        do {                                                                       \
            *(uint4*)(Arow + ((ch * 32 + 0)  ^ swp)) = g0;                         \
            *(uint4*)(Arow + ((ch * 32 + 16) ^ swp)) = g1;                         \
            *(uint4*)(Arow + ((128 + ch * 32 + 0) ^ swp)) =                        \
                make_uint4(beta_pair(g0.x, g2.x, g4.x, g6.x),                      \
                           beta_pair(g0.y, g2.y, g4.y, g6.y),                      \
                           beta_pair(g0.z, g2.z, g4.z, g6.z),                      \
                           beta_pair(g0.w, g2.w, g4.w, g6.w));                     \
            *(uint4*)(Arow + ((128 + ch * 32 + 16) ^ swp)) =                       \
                make_uint4(beta_pair(g1.x, g3.x, g5.x, g7.x),                      \
                           beta_pair(g1.y, g3.y, g5.y, g7.y),                      \
                           beta_pair(g1.z, g3.z, g5.z, g7.z),                      \
                           beta_pair(g1.w, g3.w, g5.w, g7.w));                     \
        } while (0)

    // MFMA over current Asm + per-tile epilogue
    #define MFMA_EPI(i)                                                            \
        do {                                                                       \
            f32x4 acc[8];                                                          \
            _Pragma("unroll")                                                      \
            for (int s = 0; s < 8; ++s) acc[s] = (f32x4){bv[s], bv[s], bv[s], bv[s]}; \
            _Pragma("unroll")                                                      \
            for (int kk = 0; kk < 4; ++kk) {                                       \
                const int koff = kk * 64 + kg * 16;                                \
                const short8 af = *(const short8*)(ArowR + (koff ^ swl));          \
                _Pragma("unroll")                                                  \
                for (int s = 0; s < 8; ++s) {                                      \
                    const short8 bf = *(const short8*)(Wsm + (s * 16 + col16) * 256 \
                                                        + (koff ^ swl));           \
                    acc[s] = __builtin_amdgcn_mfma_f32_16x16x32_bf16(af, bf, acc[s], 0, 0, 0); \
                }                                                                  \
            }                                                                      \
            if (MODE == 0) {                                                       \
                _Pragma("unroll")                                                  \
                for (int s = 0; s < 8; ++s) {                                      \
                    ps[s] += acc[s].x + acc[s].y + acc[s].z + acc[s].w;            \
                    pq[s] += acc[s].x * acc[s].x + acc[s].y * acc[s].y             \
                           + acc[s].z * acc[s].z + acc[s].w * acc[s].w;            \
                }                                                                  \
            } else {                                                               \
                const int fbase = (tloc + (i)) * 64 + w * 16 + kg * 4;             \
                _Pragma("unroll")                                                  \
                for (int s = 0; s < 8; ++s) {                                      \
                    const int o = s * 16 + col16;                                  \
                    f32x4 v = acc[s];                                              \
                    v.x = fmaxf(fmaf(v.x, scv[s], shv[s]), 0.f);                   \
                    v.y = fmaxf(fmaf(v.y, scv[s], shv[s]), 0.f);                   \
                    v.z = fmaxf(fmaf(v.z, scv[s], shv[s]), 0.f);                   \
                    v.w = fmaxf(fmaf(v.w, scv[s], shv[s]), 0.f);                   \
                    __builtin_nontemporal_store(v,                                  \
                        (f32x4*)(y + ((size_t)b * O_DIM + o) * F_DIM + fbase));    \
                }                                                                  \
            }                                                                      \
        } while (0)

    // ---- pipelined tile loop (manually unrolled; 2 barriers per tile) ----
    WRITE_A();  __syncthreads();  ISSUE(a1);  MFMA_EPI(0);  __syncthreads();
    WRITE_A();  __syncthreads();  ISSUE(a2);  MFMA_EPI(1);  __syncthreads();
    WRITE_A();  __syncthreads();  ISSUE(a3);  MFMA_EPI(2);  __syncthreads();
    WRITE_A();  __syncthreads();  ISSUE(a4_); MFMA_EPI(3);  __syncthreads();
    WRITE_A();  __syncthreads();  ISSUE(a5);  MFMA_EPI(4);  __syncthreads();
    WRITE_A();  __syncthreads();  ISSUE(a6);  MFMA_EPI(5);  __syncthreads();
    WRITE_A();  __syncthreads();  ISSUE(a7);  MFMA_EPI(6);  __syncthreads();
    WRITE_A();  __syncthreads();              MFMA_EPI(7);

    #undef ISSUE
    #undef WRITE_A
    #undef MFMA_EPI

    if (MODE == 0) {
        __shared__ float sm_s[4][128];
        __shared__ float sm_q[4][128];
        __syncthreads();
        #pragma unroll
        for (int s = 0; s < 8; ++s) {
            float a = ps[s], c = pq[s];
            a += __shfl_xor(a, 16, 64);  c += __shfl_xor(c, 16, 64);
            a += __shfl_xor(a, 32, 64);  c += __shfl_xor(c, 32, 64);
            if (kg == 0) {
                sm_s[w][s * 16 + col16] = a;
                sm_q[w][s * 16 + col16] = c;
            }
        }
        __syncthreads();
        if (t < 128) {
            const float a = sm_s[0][t] + sm_s[1][t] + sm_s[2][t] + sm_s[3][t];
            const float c = sm_q[0][t] + sm_q[1][t] + sm_q[2][t] + sm_q[3][t];
            part[(size_t)t * NBLK3 + bid]         = a;
            part[(size_t)(128 + t) * NBLK3 + bid] = c;
        }
    }
}

// ------------- Pass 3: reduce partials + finalize scale/shift ---------------
__global__ __launch_bounds__(256) void k_reduce_finalize(const float* __restrict__ part,
                                                         const float* __restrict__ gamma,
                                                         const float* __restrict__ beta_bn,
                                                         float* __restrict__ ss) {
    const int o = blockIdx.x;
    const int t = threadIdx.x;
    const float4* p1 = (const float4*)(part + (size_t)o * NBLK3);
    const float4* p2 = (const float4*)(part + (size_t)(128 + o) * NBLK3);
    float s = 0.f, q = 0.f;
    for (int i = t; i < NBLK3 / 4; i += 256) {
        const float4 v = p1[i];
        s += v.x + v.y + v.z + v.w;
        const float4 u = p2[i];
        q += u.x + u.y + u.z + u.w;
    }
    #pragma unroll
    for (int off = 32; off > 0; off >>= 1) {
        s += __shfl_down(s, off, 64);
        q += __shfl_down(q, off, 64);
    }
    __shared__ float ls[8];
    const int wid = t >> 6, lane = t & 63;
    if (lane == 0) { ls[wid] = s; ls[4 + wid] = q; }
    __syncthreads();
    if (t == 0) {
        const float ts = ls[0] + ls[1] + ls[2] + ls[3];
        const float tq = ls[4] + ls[5] + ls[6] + ls[7];
        const float n    = (float)B_DIM * (float)F_DIM;
        const float mean = ts / n;
        const float var  = tq / n - mean * mean;
        const float sc   = gamma[o] * rsqrtf(var + 1e-5f);
        ss[o]         = sc;
        ss[O_DIM + o] = beta_bn[o] - mean * sc;
    }
}

// ================== fallback path (small ws) — round-1 known-correct ========
__global__ __launch_bounds__(256) void k_compute_slow(const float* __restrict__ xsrc,
                                                      const int*   __restrict__ adj,
                                                      const float* __restrict__ W,
                                                      const float* __restrict__ bias,
                                                      float*       __restrict__ y) {
    const int b = blockIdx.y;
    const int f = blockIdx.x * 256 + threadIdx.x;
    const int4 a = ((const int4*)adj)[(size_t)b * F_DIM + f];
    float tg[64], bt[64];
    const float* base = xsrc + (size_t)b * C_DIM * F_DIM;
    #pragma unroll
    for (int c = 0; c < 64; ++c) {
        const float tv = base[(size_t)c * F_DIM + a.x];
        const float n1 = base[(size_t)c * F_DIM + a.y];
        const float n2 = base[(size_t)c * F_DIM + a.z];
        const float n3 = base[(size_t)c * F_DIM + a.w];
        tg[c] = tv;
        bt[c] = fabsf(tv - n1) + fabsf(tv - n2) + fabsf(tv - n3);
    }
    float* yb = y + (size_t)b * O_DIM * F_DIM + f;
    const float2* W2 = (const float2*)W;
    #pragma unroll 4
    for (int o = 0; o < O_DIM; ++o) {
        float acc = bias[o];
        #pragma unroll
        for (int c = 0; c < 64; ++c) {
            const float2 wv = W2[o * 64 + c];
            acc = fmaf(tg[c], wv.x, fmaf(bt[c], wv.y, acc));
        }
        yb[(size_t)o * F_DIM] = acc;
    }
}

__global__ __launch_bounds__(256) void k_stats(const float* __restrict__ y,
                                               float* __restrict__ stats) {
    const int o = blockIdx.x;
    const int b = blockIdx.y;
    const float4* row = (const float4*)(y + ((size_t)b * O_DIM + o) * F_DIM);
    float s = 0.f, s2 = 0.f;
    for (int i = threadIdx.x; i < F_DIM / 4; i += 256) {
        const float4 v = row[i];
        s  += v.x + v.y + v.z + v.w;
        s2 += v.x * v.x + v.y * v.y + v.z * v.z + v.w * v.w;
    }
    #pragma unroll
    for (int off = 32; off > 0; off >>= 1) {
        s  += __shfl_down(s,  off, 64);
        s2 += __shfl_down(s2, off, 64);
    }
    __shared__ float ls[4], ls2[4];
    const int wid = threadIdx.x >> 6, lane = threadIdx.x & 63;
    if (lane == 0) { ls[wid] = s; ls2[wid] = s2; }
    __syncthreads();
    if (threadIdx.x == 0) {
        atomicAdd(&stats[o],         ls[0] + ls[1] + ls[2] + ls[3]);
        atomicAdd(&stats[O_DIM + o], ls2[0] + ls2[1] + ls2[2] + ls2[3]);
    }
}

__global__ void k_finalize(const float* __restrict__ stats,
                           const float* __restrict__ gamma,
                           const float* __restrict__ beta_bn,
                           float* __restrict__ ss) {
    const int o = threadIdx.x;
    if (o < O_DIM) {
        const float n    = (float)B_DIM * (float)F_DIM;
        const float mean = stats[o] / n;
        const float var  = stats[O_DIM + o] / n - mean * mean;
        const float sc   = gamma[o] * rsqrtf(var + 1e-5f);
        ss[o]         = sc;
        ss[O_DIM + o] = beta_bn[o] - mean * sc;
    }
}

__global__ __launch_bounds__(256) void k_norm(float* __restrict__ y,
                                              const float* __restrict__ ss) {
    const size_t n4 = (size_t)B_DIM * O_DIM * F_DIM / 4;
    const size_t stride = (size_t)gridDim.x * blockDim.x;
    float4* y4 = (float4*)y;
    for (size_t i = (size_t)blockIdx.x * blockDim.x + threadIdx.x; i < n4; i += stride) {
        const int o = (int)((i >> 12) & (O_DIM - 1));
        const float sc = ss[o];
        const float sh = ss[O_DIM + o];
        float4 v = y4[i];
        v.x = fmaxf(fmaf(v.x, sc, sh), 0.f);
        v.y = fmaxf(fmaf(v.y, sc, sh), 0.f);
        v.z = fmaxf(fmaf(v.z, sc, sh), 0.f);
        v.w = fmaxf(fmaf(v.w, sc, sh), 0.f);
        y4[i] = v;
    }
}

extern "C" void kernel_launch(void* const* d_in, const int* in_sizes, int n_in,
                              void* d_out, int out_size, void* d_ws, size_t ws_size,
                              hipStream_t stream) {
    const float* x       = (const float*)d_in[0];
    const int*   adj     = (const int*)  d_in[1];
    const float* W       = (const float*)d_in[2];
    const float* bias    = (const float*)d_in[3];
    const float* gamma   = (const float*)d_in[4];
    const float* beta_bn = (const float*)d_in[5];
    float* out = (float*)d_out;

    const size_t XT_B   = (size_t)B_DIM * F_DIM * C_DIM * 2;            // 64 MB
    const size_t PART_B = (size_t)2 * O_DIM * NBLK3 * sizeof(float);    // 1 MB

    float*  stats = (float*)d_ws;
    float*  ss    = (float*)((char*)d_ws + 1024);
    ushort* Wtg   = (ushort*)((char*)d_ws + 4096);
    ushort* xt    = (ushort*)((char*)d_ws + 65536);
    float*  part  = (float*)((char*)d_ws + 65536 + XT_B);

    const size_t need = 65536 + XT_B + PART_B;

    if (ws_size >= need) {
        k_transpose<<<dim3(F_DIM / 64, B_DIM), 256, 0, stream>>>(x, xt, W, Wtg);
        k_compute_t<0><<<dim3(NBLK3), 256, 0, stream>>>(xt, adj, Wtg, bias, nullptr, nullptr, part);
        k_reduce_finalize<<<O_DIM, 256, 0, stream>>>(part, gamma, beta_bn, ss);
        k_compute_t<1><<<dim3(NBLK3), 256, 0, stream>>>(xt, adj, Wtg, bias, ss, out, nullptr);
    } else {
        hipMemsetAsync(stats, 0, 2 * O_DIM * sizeof(float), stream);
        k_compute_slow<<<dim3(F_DIM / 256, B_DIM), 256, 0, stream>>>(x, adj, W, bias, out);
        k_stats<<<dim3(O_DIM, B_DIM), 256, 0, stream>>>(out, stats);
        k_finalize<<<1, 128, 0, stream>>>(stats, gamma, beta_bn, ss);
        k_norm<<<2048, 256, 0, stream>>>(out, ss);
    }
}

// Round 11
// 174.818 us; speedup vs baseline: 1.1939x; 1.1934x over previous
//
#include <hip/hip_runtime.h>

#define B_DIM 32
#define C_DIM 64
#define F_DIM 16384
#define O_DIM 128
#define NBLK4 ((F_DIM / 128) * B_DIM)   // 4096 compute blocks (128 points each)

typedef __attribute__((ext_vector_type(8))) short short8;
typedef __attribute__((ext_vector_type(4))) float f32x4;

__device__ __forceinline__ ushort f2bf(float f) {
    union { float f; uint u; } v; v.f = f;
    return (ushort)((v.u + 0x7FFFu + ((v.u >> 16) & 1u)) >> 16);
}
__device__ __forceinline__ float bflo(uint u) {
    union { uint u; float f; } v; v.u = u << 16; return v.f;
}
__device__ __forceinline__ float bfhi(uint u) {
    union { uint u; float f; } v; v.u = u & 0xFFFF0000u; return v.f;
}
__device__ __forceinline__ uint beta_pair(uint tu, uint au, uint bu, uint cu) {
    const float tl = bflo(tu), th = bfhi(tu);
    const float lo = fabsf(tl - bflo(au)) + fabsf(tl - bflo(bu)) + fabsf(tl - bflo(cu));
    const float hi = fabsf(th - bfhi(au)) + fabsf(th - bfhi(bu)) + fabsf(th - bfhi(cu));
    return (uint)f2bf(lo) | ((uint)f2bf(hi) << 16);
}

// ------- Pass 1: transpose x (B,C,F) fp32 -> xt (B,F,C) bf16  (+W prep) -----
__global__ __launch_bounds__(256) void k_transpose(const float* __restrict__ x,
                                                   ushort* __restrict__ xt,
                                                   const float* __restrict__ W,
                                                   ushort* __restrict__ Wtg) {
    __shared__ float tile[64][65];
    const int b  = blockIdx.y;
    const int f0 = blockIdx.x * 64;
    const int t  = threadIdx.x;
    const int fl = t & 63;
    const int q  = t >> 6;

    const float* xb = x + (size_t)b * C_DIM * F_DIM;
    #pragma unroll
    for (int i = 0; i < 16; ++i) {
        const int c = q + i * 4;
        tile[c][fl] = __builtin_nontemporal_load(&xb[(size_t)c * F_DIM + f0 + fl]);
    }

    if (blockIdx.x == 0 && blockIdx.y == 0 && t < 128) {
        const int o = t;
        #pragma unroll 8
        for (int c = 0; c < C_DIM; ++c) {
            Wtg[o * 128 + c]      = f2bf(W[o * 128 + c * 2]);
            Wtg[o * 128 + 64 + c] = f2bf(W[o * 128 + c * 2 + 1]);
        }
    }

    __syncthreads();

    const int f  = t >> 2;
    const int ch = t & 3;
    union { ushort s[16]; uint4 v[2]; } u;
    #pragma unroll
    for (int j = 0; j < 16; ++j)
        u.s[j] = f2bf(tile[ch * 16 + j][f]);
    ushort* dst = xt + ((size_t)b * F_DIM + f0 + f) * C_DIM + ch * 16;
    *(uint4*)(dst)     = u.v[0];
    *(uint4*)(dst + 8) = u.v[1];
}

// ------------- Pass 2/4: gather + beta + MFMA GEMM (round-8 structure, ------
// widened to 512 threads / 8 waves / 128-point A tile for +33% occupancy).
// MODE 0: accumulate per-block (sum,sumsq) per o -> part, no y store.
// MODE 1: apply scale/shift (ss) + ReLU, store final y (nontemporal).
template <int MODE>
__global__ __launch_bounds__(512, 4) void k_compute_t(const ushort* __restrict__ xt,
                                                      const int*    __restrict__ adj,
                                                      const ushort* __restrict__ Wtg,
                                                      const float*  __restrict__ bias,
                                                      const float*  __restrict__ ss,
                                                      float*        __restrict__ y,
                                                      float*        __restrict__ part) {
    __shared__ __align__(16) char Asm[128 * 256];   // A tile: 128 rows x 128 bf16 (swizzled)
    __shared__ __align__(16) char Wsm[128 * 256];   // Wt:    128 rows x 128 bf16 (swizzled)

    const int bid = blockIdx.x;
    const int tg  = (bid & 7) * (NBLK4 / 8) + (bid >> 3);   // XCD-aware, bijective
    const int b   = tg >> 7;                                 // 128 tiles per batch
    const int f0  = (tg & 127) * 128;
    const int t   = threadIdx.x;

    // --- issue all 8 scattered gather loads FIRST (latency overlap) ---
    const int p  = t >> 2;          // point 0..127
    const int ch = t & 3;           // 32B c-chunk
    const int4 a4 = ((const int4*)adj)[(size_t)b * F_DIM + f0 + p];
    const char* xb = (const char*)(xt + (size_t)b * F_DIM * C_DIM);
    const char* r0 = xb + (size_t)a4.x * 128 + ch * 32;
    const char* r1 = xb + (size_t)a4.y * 128 + ch * 32;
    const char* r2 = xb + (size_t)a4.z * 128 + ch * 32;
    const char* r3 = xb + (size_t)a4.w * 128 + ch * 32;
    uint4 g[8];
    g[0] = *(const uint4*)(r0);  g[1] = *(const uint4*)(r0 + 16);
    g[2] = *(const uint4*)(r1);  g[3] = *(const uint4*)(r1 + 16);
    g[4] = *(const uint4*)(r2);  g[5] = *(const uint4*)(r2 + 16);
    g[6] = *(const uint4*)(r3);  g[7] = *(const uint4*)(r3 + 16);

    // --- stage Wt into swizzled LDS (512 threads x 4 x 16B = 32 KB) ---
    {
        const uint4* src = (const uint4*)Wtg;
        #pragma unroll
        for (int jj = 0; jj < 4; ++jj) {
            const int fb    = t * 64 + jj * 16;
            const int o     = fb >> 8;
            const int inner = fb & 255;
            *(uint4*)(Wsm + (o << 8) + (inner ^ ((o & 7) << 4))) = src[fb >> 4];
        }
    }

    // --- beta + A-tile store (swizzled) ---
    {
        const int sw = (p & 7) << 4;
        char* Arow = Asm + p * 256;
        #pragma unroll
        for (int h = 0; h < 2; ++h) {
            const uint4 t0 = g[h], n1 = g[2 + h], n2 = g[4 + h], n3 = g[6 + h];
            *(uint4*)(Arow + ((ch * 32 + h * 16) ^ sw)) = t0;   // target bits
            const uint tu[4] = { t0.x, t0.y, t0.z, t0.w };
            const uint au[4] = { n1.x, n1.y, n1.z, n1.w };
            const uint bu[4] = { n2.x, n2.y, n2.z, n2.w };
            const uint cu[4] = { n3.x, n3.y, n3.z, n3.w };
            uint bt[4];
            #pragma unroll
            for (int qq = 0; qq < 4; ++qq)
                bt[qq] = beta_pair(tu[qq], au[qq], bu[qq], cu[qq]);
            *(uint4*)(Arow + ((128 + ch * 32 + h * 16) ^ sw)) =
                make_uint4(bt[0], bt[1], bt[2], bt[3]);
        }
    }

    __syncthreads();

    // --- MFMA: wave w (0..7) owns m-rows [w*16, w*16+16), all 128 o ---
    const int w     = t >> 6;
    const int l     = t & 63;
    const int col16 = l & 15;
    const int kg    = l >> 4;
    const int swl   = (l & 7) << 4;

    f32x4 acc[8];
    #pragma unroll
    for (int s = 0; s < 8; ++s) {
        const float bv = bias[s * 16 + col16];
        acc[s] = (f32x4){ bv, bv, bv, bv };
    }

    const char* ArowR = Asm + (w * 16 + col16) * 256;
    #pragma unroll
    for (int kk = 0; kk < 4; ++kk) {
        const int koff = kk * 64 + kg * 16;
        const short8 af = *(const short8*)(ArowR + (koff ^ swl));
        #pragma unroll
        for (int s = 0; s < 8; ++s) {
            const short8 bf = *(const short8*)(Wsm + (s * 16 + col16) * 256 + (koff ^ swl));
            acc[s] = __builtin_amdgcn_mfma_f32_16x16x32_bf16(af, bf, acc[s], 0, 0, 0);
        }
    }

    if (MODE == 0) {
        // --- reduce acc -> per-block (sum,sumsq) per o, write partials ---
        __shared__ float sm_s[8][128];
        __shared__ float sm_q[8][128];
        #pragma unroll
        for (int s = 0; s < 8; ++s) {
            float ps = acc[s].x + acc[s].y + acc[s].z + acc[s].w;
            float pq = acc[s].x * acc[s].x + acc[s].y * acc[s].y
                     + acc[s].z * acc[s].z + acc[s].w * acc[s].w;
            ps += __shfl_xor(ps, 16, 64);  pq += __shfl_xor(pq, 16, 64);
            ps += __shfl_xor(ps, 32, 64);  pq += __shfl_xor(pq, 32, 64);
            if (kg == 0) {
                sm_s[w][s * 16 + col16] = ps;
                sm_q[w][s * 16 + col16] = pq;
            }
        }
        __syncthreads();
        if (t < 128) {
            float a = 0.f, c = 0.f;
            #pragma unroll
            for (int ww = 0; ww < 8; ++ww) { a += sm_s[ww][t]; c += sm_q[ww][t]; }
            part[(size_t)t * NBLK4 + bid]         = a;
            part[(size_t)(128 + t) * NBLK4 + bid] = c;
        }
    } else {
        // MODE 1: normalize + ReLU + coalesced nontemporal float4 stores
        const int fbase = f0 + w * 16 + kg * 4;
        #pragma unroll
        for (int s = 0; s < 8; ++s) {
            const int o = s * 16 + col16;
            const float sc = ss[o];
            const float sh = ss[O_DIM + o];
            f32x4 v = acc[s];
            v.x = fmaxf(fmaf(v.x, sc, sh), 0.f);
            v.y = fmaxf(fmaf(v.y, sc, sh), 0.f);
            v.z = fmaxf(fmaf(v.z, sc, sh), 0.f);
            v.w = fmaxf(fmaf(v.w, sc, sh), 0.f);
            __builtin_nontemporal_store(v, (f32x4*)(y + ((size_t)b * O_DIM + o) * F_DIM + fbase));
        }
    }
}

// ------------- Pass 3: reduce partials + finalize scale/shift ---------------
__global__ __launch_bounds__(256) void k_reduce_finalize(const float* __restrict__ part,
                                                         const float* __restrict__ gamma,
                                                         const float* __restrict__ beta_bn,
                                                         float* __restrict__ ss) {
    const int o = blockIdx.x;
    const int t = threadIdx.x;
    const float4* p1 = (const float4*)(part + (size_t)o * NBLK4);
    const float4* p2 = (const float4*)(part + (size_t)(128 + o) * NBLK4);
    float s = 0.f, q = 0.f;
    for (int i = t; i < NBLK4 / 4; i += 256) {
        const float4 v = p1[i];
        s += v.x + v.y + v.z + v.w;
        const float4 u = p2[i];
        q += u.x + u.y + u.z + u.w;
    }
    #pragma unroll
    for (int off = 32; off > 0; off >>= 1) {
        s += __shfl_down(s, off, 64);
        q += __shfl_down(q, off, 64);
    }
    __shared__ float ls[8];
    const int wid = t >> 6, lane = t & 63;
    if (lane == 0) { ls[wid] = s; ls[4 + wid] = q; }
    __syncthreads();
    if (t == 0) {
        const float ts = ls[0] + ls[1] + ls[2] + ls[3];
        const float tq = ls[4] + ls[5] + ls[6] + ls[7];
        const float n    = (float)B_DIM * (float)F_DIM;
        const float mean = ts / n;
        const float var  = tq / n - mean * mean;
        const float sc   = gamma[o] * rsqrtf(var + 1e-5f);
        ss[o]         = sc;
        ss[O_DIM + o] = beta_bn[o] - mean * sc;
    }
}

// ================== fallback path (small ws) — round-1 known-correct ========
__global__ __launch_bounds__(256) void k_compute_slow(const float* __restrict__ xsrc,
                                                      const int*   __restrict__ adj,
                                                      const float* __restrict__ W,
                                                      const float* __restrict__ bias,
                                                      float*       __restrict__ y) {
    const int b = blockIdx.y;
    const int f = blockIdx.x * 256 + threadIdx.x;
    const int4 a = ((const int4*)adj)[(size_t)b * F_DIM + f];
    float tg[64], bt[64];
    const float* base = xsrc + (size_t)b * C_DIM * F_DIM;
    #pragma unroll
    for (int c = 0; c < 64; ++c) {
        const float tv = base[(size_t)c * F_DIM + a.x];
        const float n1 = base[(size_t)c * F_DIM + a.y];
        const float n2 = base[(size_t)c * F_DIM + a.z];
        const float n3 = base[(size_t)c * F_DIM + a.w];
        tg[c] = tv;
        bt[c] = fabsf(tv - n1) + fabsf(tv - n2) + fabsf(tv - n3);
    }
    float* yb = y + (size_t)b * O_DIM * F_DIM + f;
    const float2* W2 = (const float2*)W;
    #pragma unroll 4
    for (int o = 0; o < O_DIM; ++o) {
        float acc = bias[o];
        #pragma unroll
        for (int c = 0; c < 64; ++c) {
            const float2 wv = W2[o * 64 + c];
            acc = fmaf(tg[c], wv.x, fmaf(bt[c], wv.y, acc));
        }
        yb[(size_t)o * F_DIM] = acc;
    }
}

__global__ __launch_bounds__(256) void k_stats(const float* __restrict__ y,
                                               float* __restrict__ stats) {
    const int o = blockIdx.x;
    const int b = blockIdx.y;
    const float4* row = (const float4*)(y + ((size_t)b * O_DIM + o) * F_DIM);
    float s = 0.f, s2 = 0.f;
    for (int i = threadIdx.x; i < F_DIM / 4; i += 256) {
        const float4 v = row[i];
        s  += v.x + v.y + v.z + v.w;
        s2 += v.x * v.x + v.y * v.y + v.z * v.z + v.w * v.w;
    }
    #pragma unroll
    for (int off = 32; off > 0; off >>= 1) {
        s  += __shfl_down(s,  off, 64);
        s2 += __shfl_down(s2, off, 64);
    }
    __shared__ float ls[4], ls2[4];
    const int wid = threadIdx.x >> 6, lane = threadIdx.x & 63;
    if (lane == 0) { ls[wid] = s; ls2[wid] = s2; }
    __syncthreads();
    if (threadIdx.x == 0) {
        atomicAdd(&stats[o],         ls[0] + ls[1] + ls[2] + ls[3]);
        atomicAdd(&stats[O_DIM + o], ls2[0] + ls2[1] + ls2[2] + ls2[3]);
    }
}

__global__ void k_finalize(const float* __restrict__ stats,
                           const float* __restrict__ gamma,
                           const float* __restrict__ beta_bn,
                           float* __restrict__ ss) {
    const int o = threadIdx.x;
    if (o < O_DIM) {
        const float n    = (float)B_DIM * (float)F_DIM;
        const float mean = stats[o] / n;
        const float var  = stats[O_DIM + o] / n - mean * mean;
        const float sc   = gamma[o] * rsqrtf(var + 1e-5f);
        ss[o]         = sc;
        ss[O_DIM + o] = beta_bn[o] - mean * sc;
    }
}

__global__ __launch_bounds__(256) void k_norm(float* __restrict__ y,
                                              const float* __restrict__ ss) {
    const size_t n4 = (size_t)B_DIM * O_DIM * F_DIM / 4;
    const size_t stride = (size_t)gridDim.x * blockDim.x;
    float4* y4 = (float4*)y;
    for (size_t i = (size_t)blockIdx.x * blockDim.x + threadIdx.x; i < n4; i += stride) {
        const int o = (int)((i >> 12) & (O_DIM - 1));
        const float sc = ss[o];
        const float sh = ss[O_DIM + o];
        float4 v = y4[i];
        v.x = fmaxf(fmaf(v.x, sc, sh), 0.f);
        v.y = fmaxf(fmaf(v.y, sc, sh), 0.f);
        v.z = fmaxf(fmaf(v.z, sc, sh), 0.f);
        v.w = fmaxf(fmaf(v.w, sc, sh), 0.f);
        y4[i] = v;
    }
}

extern "C" void kernel_launch(void* const* d_in, const int* in_sizes, int n_in,
                              void* d_out, int out_size, void* d_ws, size_t ws_size,
                              hipStream_t stream) {
    const float* x       = (const float*)d_in[0];
    const int*   adj     = (const int*)  d_in[1];
    const float* W       = (const float*)d_in[2];
    const float* bias    = (const float*)d_in[3];
    const float* gamma   = (const float*)d_in[4];
    const float* beta_bn = (const float*)d_in[5];
    float* out = (float*)d_out;

    const size_t XT_B   = (size_t)B_DIM * F_DIM * C_DIM * 2;            // 64 MB
    const size_t PART_B = (size_t)2 * O_DIM * NBLK4 * sizeof(float);    // 4 MB

    float*  stats = (float*)d_ws;
    float*  ss    = (float*)((char*)d_ws + 1024);
    ushort* Wtg   = (ushort*)((char*)d_ws + 4096);
    ushort* xt    = (ushort*)((char*)d_ws + 65536);
    float*  part  = (float*)((char*)d_ws + 65536 + XT_B);

    const size_t need = 65536 + XT_B + PART_B;

    if (ws_size >= need) {
        k_transpose<<<dim3(F_DIM / 64, B_DIM), 256, 0, stream>>>(x, xt, W, Wtg);
        k_compute_t<0><<<dim3(NBLK4), 512, 0, stream>>>(xt, adj, Wtg, bias, nullptr, nullptr, part);
        k_reduce_finalize<<<O_DIM, 256, 0, stream>>>(part, gamma, beta_bn, ss);
        k_compute_t<1><<<dim3(NBLK4), 512, 0, stream>>>(xt, adj, Wtg, bias, ss, out, nullptr);
    } else {
        hipMemsetAsync(stats, 0, 2 * O_DIM * sizeof(float), stream);
        k_compute_slow<<<dim3(F_DIM / 256, B_DIM), 256, 0, stream>>>(x, adj, W, bias, out);
        k_stats<<<dim3(O_DIM, B_DIM), 256, 0, stream>>>(out, stats);
        k_finalize<<<1, 128, 0, stream>>>(stats, gamma, beta_bn, ss);
        k_norm<<<2048, 256, 0, stream>>>(out, ss);
    }
}